// Round 1
// baseline (3111.509 us; speedup 1.0000x reference)
//
#include <hip/hip_runtime.h>
#include <stdint.h>

#define BN_ 2
#define NPT 16384
#define MPT 8192
#define NROI 128
#define KP 2048
#define CAP 5184   // LDS capacity for compacted valid points (3*CAP*4 = 62208 B)

// ---- workspace layout (float offsets) ----
#define FEATS_LEN (4096*352)
#define CNTR_OFF  (FEATS_LEN)
#define CNTC_OFF  (CNTR_OFF + 4096)
#define FRAW_OFF  (CNTC_OFF + 4096)
#define FRAW_LEN  (BN_*NPT*32)
#define GC3_OFF   (FRAW_OFF + FRAW_LEN)
#define GC3_LEN   (BN_*MPT*64)
#define FLAGS_F_OFF (GC3_OFF + GC3_LEN)      // flags stored as bytes at this float offset
#define OUT_KP_OFF (4096*128)                // keypoints region inside d_out

// ---------------- helpers ----------------
__device__ __forceinline__ unsigned ordf(float f) {
    unsigned b = __float_as_uint(f);
    return b ^ ((unsigned)(((int)b) >> 31) | 0x80000000u);
}
__device__ __forceinline__ unsigned long long shflxor64(unsigned long long v, int m) {
    unsigned lo = __shfl_xor((unsigned)v, m, 64);
    unsigned hi = __shfl_xor((unsigned)(v >> 32), m, 64);
    return ((unsigned long long)hi << 32) | lo;
}
__device__ __forceinline__ unsigned long long wave_max64(unsigned long long k) {
#pragma unroll
    for (int m = 32; m >= 1; m >>= 1) {
        unsigned long long o = shflxor64(k, m);
        if (o > k) k = o;
    }
    return k;
}

// ---------------- K1: ROI validity flags (bit-exact vs reference) ----------------
__global__ void k_flags(const float* __restrict__ pts, const float* __restrict__ bbox,
                        unsigned char* __restrict__ flags) {
#pragma clang fp contract(off)
    __shared__ float rx[NROI], ry[NROI], rz[NROI], rt[NROI];
    int b = blockIdx.x >> 6;
    int t = threadIdx.x;
    if (t < NROI) {
        const float* rr = bbox + (size_t)(b * NROI + t) * 7;
        rx[t] = rr[0]; ry[t] = rr[1]; rz[t] = rr[2];
        float hx = rr[3] * 0.5f, hy = rr[4] * 0.5f, hz = rr[5] * 0.5f;
        rt[t] = sqrtf(((hx * hx) + (hy * hy)) + (hz * hz)) + 2.4f;
    }
    __syncthreads();
    int p = (blockIdx.x & 63) * 256 + t;
    const float* pr = pts + (size_t)(b * NPT + p) * 5;
    float x = pr[0], y = pr[1], z = pr[2];
    float mind = 3.4e38f, th = 0.f;
    for (int r = 0; r < NROI; ++r) {
        float dx = x - rx[r], dy = y - ry[r], dz = z - rz[r];
        float ds = sqrtf(((dx * dx) + (dy * dy)) + (dz * dz));
        if (ds < mind) { mind = ds; th = rt[r]; }   // strict < : first-min == np.argmin
    }
    flags[b * NPT + p] = (mind < th) ? 1 : 0;
}

// ---------------- K2: compaction + exact FPS (one block per batch) ----------------
__global__ void __launch_bounds__(1024, 1)
k_fps(const float* __restrict__ pts, const unsigned char* __restrict__ flags,
      float* __restrict__ kpOut) {
#pragma clang fp contract(off)
    __shared__ float sx[CAP], sy[CAP], sz[CAP];
    __shared__ unsigned long long red[2][16];
    __shared__ int wtot[16];
    __shared__ float sbx, sby, sbz;

    int b = blockIdx.x;
    int t = threadIdx.x;
    int lane = t & 63, w = t >> 6;
    int chunk = t * 16;
    const float* pbase = pts + (size_t)b * NPT * 5;
    const unsigned char* fbase = flags + b * NPT;

    // Phase A: per-thread contiguous chunk, count valid, block scan, compact to LDS
    float lx[16], ly[16], lz[16];
    unsigned flb = 0;
    int cnt = 0;
#pragma unroll
    for (int j = 0; j < 16; ++j) {
        const float* pr = pbase + (size_t)(chunk + j) * 5;
        lx[j] = pr[0]; ly[j] = pr[1]; lz[j] = pr[2];
        unsigned f = fbase[chunk + j];
        flb |= (f ? 1u : 0u) << j;
        cnt += f ? 1 : 0;
    }
    int incl = cnt;
#pragma unroll
    for (int off = 1; off < 64; off <<= 1) {
        int v = __shfl_up(incl, off, 64);
        if (lane >= off) incl += v;
    }
    if (lane == 63) wtot[w] = incl;
    __syncthreads();
    int waveBase = 0, V = 0;
    for (int i = 0; i < 16; ++i) { int wv = wtot[i]; V += wv; if (i < w) waveBase += wv; }
    bool fast = (V <= CAP);
    int base = waveBase + incl - cnt;
    if (fast) {
        int pos = base;
#pragma unroll
        for (int j = 0; j < 16; ++j)
            if ((flb >> j) & 1u) { sx[pos] = lx[j]; sy[pos] = ly[j]; sz[pos] = lz[j]; ++pos; }
    }
    __syncthreads();

    // slot init
    float px[16], py[16], pz[16], d[16];
    int jm;
    if (fast) {
        jm = (V + 1023) >> 10;
#pragma unroll
        for (int j = 0; j < 16; ++j) {
            if (j < jm) {
                int id = t + (j << 10);
                if (id < V) { px[j] = sx[id]; py[j] = sy[id]; pz[j] = sz[id]; d[j] = 1e10f; }
                else        { px[j] = 1e18f; py[j] = 1e18f; pz[j] = 1e18f; d[j] = -3e38f; }
            }
        }
    } else {
        jm = 16;
#pragma unroll
        for (int j = 0; j < 16; ++j) {
            const float* pr = pbase + (size_t)(chunk + j) * 5;
            px[j] = pr[0]; py[j] = pr[1]; pz[j] = pr[2];
            d[j] = ((flb >> j) & 1u) ? 1e10f : -3e38f;
        }
    }

    // prime: argmax over initial d
    float bestD = -3.4e38f; int bestJ = 0;
#pragma unroll
    for (int j = 0; j < 16; ++j)
        if (j < jm) { if (d[j] > bestD) { bestD = d[j]; bestJ = j; } }
    unsigned gid = fast ? (unsigned)(t + (bestJ << 10)) : (unsigned)(chunk + bestJ);
    unsigned long long key =
        ((unsigned long long)ordf(bestD) << 32) | (unsigned)(0xFFFFFFFFu - gid);
    key = wave_max64(key);
    if (lane == 0) red[0][w] = key;
    __syncthreads();

    float* kout = kpOut + (size_t)b * KP * 3;
    for (int k = 0; k < KP; ++k) {
        int p = k & 1;
        // block winner from the 16 wave candidates (double-buffered)
        unsigned long long e = red[p][lane & 15];
#pragma unroll
        for (int m = 8; m >= 1; m >>= 1) {
            unsigned long long o = shflxor64(e, m);
            if (o > e) e = o;
        }
        unsigned wid = 0xFFFFFFFFu - (unsigned)(e & 0xFFFFFFFFull);
        float bx, by, bz;
        if (fast) {
            bx = sx[wid]; by = sy[wid]; bz = sz[wid];
        } else {
            int ot = (int)(wid >> 4), oj = (int)(wid & 15u);
            if (t == ot) {
#pragma unroll
                for (int j = 0; j < 16; ++j)
                    if (j == oj) { sbx = px[j]; sby = py[j]; sbz = pz[j]; }
            }
            __syncthreads();
            bx = sbx; by = sby; bz = sbz;
        }
        if (t == 0) { kout[k * 3] = bx; kout[k * 3 + 1] = by; kout[k * 3 + 2] = bz; }
        // update + fused local argmax (exact: no fp contraction)
        bestD = -3.4e38f; bestJ = 0;
#pragma unroll
        for (int j = 0; j < 16; ++j) {
            if (j < jm) {
                float dx = px[j] - bx, dy = py[j] - by, dz = pz[j] - bz;
                float nd = ((dx * dx) + (dy * dy)) + (dz * dz);
                float dn = fminf(d[j], nd);
                d[j] = dn;
                if (dn > bestD) { bestD = dn; bestJ = j; }
            }
        }
        gid = fast ? (unsigned)(t + (bestJ << 10)) : (unsigned)(chunk + bestJ);
        key = ((unsigned long long)ordf(bestD) << 32) | (unsigned)(0xFFFFFFFFu - gid);
        key = wave_max64(key);
        if (lane == 0) red[p ^ 1][w] = key;
        __syncthreads();
    }
}

// ---------------- K3: bilinear BEV sampling ----------------
__global__ void k_bilinear(const float* __restrict__ sf, const float* __restrict__ kp,
                           float* __restrict__ feats) {
    int bid = blockIdx.x;
    int b = bid >> 11, kk = bid & 2047;
    int c = threadIdx.x;
    const float* kpr = kp + (size_t)(b * KP + kk) * 3;
    float x = kpr[0], y = kpr[1];
    float xi = ((x - (-75.2f)) / 0.1f) / 8.0f;
    float yi = ((y - (-75.2f)) / 0.1f) / 8.0f;
    int x0 = (int)floorf(xi); x0 = min(max(x0, 0), 187);
    int x1 = min(max(x0 + 1, 0), 187);
    int y0 = (int)floorf(yi); y0 = min(max(y0, 0), 187);
    int y1 = min(max(y0 + 1, 0), 187);
    float xf0 = (float)x0, xf1 = (float)x1, yf0 = (float)y0, yf1 = (float)y1;
    float wa = (xf1 - xi) * (yf1 - yi), wb = (xf1 - xi) * (yi - yf0);
    float wc = (xi - xf0) * (yf1 - yi), wd = (xi - xf0) * (yi - yf0);
    const float* plane = sf + (size_t)(b * 256 + c) * 188 * 188;
    float Ia = plane[y0 * 188 + x0], Ib = plane[y1 * 188 + x0];
    float Ic = plane[y0 * 188 + x1], Id = plane[y1 * 188 + x1];
    feats[(size_t)(b * KP + kk) * 352 + c] = Ia * wa + Ib * wb + Ic * wc + Id * wd;
}

// ---------------- K4a: raw point feature MLP ----------------
__global__ void k_fraw(const float* __restrict__ pts, const float* __restrict__ Wr,
                       const float* __restrict__ br, float* __restrict__ fraw) {
    int idx = blockIdx.x * 256 + threadIdx.x;   // < BN_*NPT*32
    int c = idx & 31, n = idx >> 5;
    const float* pr = pts + (size_t)n * 5;
    float v = pr[3] * Wr[c] + pr[4] * Wr[32 + c] + br[c];
    fraw[(size_t)n * 32 + c] = fmaxf(v, 0.f);
}

// ---------------- K4b: conv3 point feature MLP ----------------
__global__ void k_gc3(const float* __restrict__ conv3, const float* __restrict__ Wc,
                      const float* __restrict__ bc, float* __restrict__ gc3) {
    __shared__ float w[4096];
    __shared__ float rf[4][64];
    int t = threadIdx.x;
    for (int i = t; i < 4096; i += 256) w[i] = Wc[i];
    int r = blockIdx.x * 4 + (t >> 6);
    int c = t & 63;
    rf[t >> 6][c] = conv3[(size_t)r * 67 + 3 + c];
    __syncthreads();
    float s = bc[c];
#pragma unroll 8
    for (int k = 0; k < 64; ++k) s = fmaf(rf[t >> 6][k], w[k * 64 + c], s);
    gc3[(size_t)r * 64 + c] = fmaxf(s, 0.f);
}

// ---------------- K5: raw radius aggregation (thread = keypoint, N split) ----------------
__global__ void k_rawagg(const float* __restrict__ pts, const float* __restrict__ kp,
                         const float* __restrict__ fraw, float* __restrict__ feats,
                         float* __restrict__ cntR) {
    __shared__ float sp[2560];
    int bid = blockIdx.x;
    int b = bid >> 7, kb = (bid >> 4) & 7, s = bid & 15;
    int t = threadIdx.x;
    int kk = kb * 256 + t, row = b * KP + kk;
    float kx = kp[row * 3], ky = kp[row * 3 + 1], kz = kp[row * 3 + 2];
    float acc[32];
#pragma unroll
    for (int c = 0; c < 32; ++c) acc[c] = 0.f;
    float cnt = 0.f;
    const float R2 = 0.8f * 0.8f;
    for (int tile = 0; tile < 2; ++tile) {
        int nbase = s * 1024 + tile * 512;
        const float* src = pts + (size_t)(b * NPT + nbase) * 5;
        for (int i = t; i < 2560; i += 256) sp[i] = src[i];
        __syncthreads();
        for (int j = 0; j < 512; ++j) {
            float dx = kx - sp[j * 5], dy = ky - sp[j * 5 + 1], dz = kz - sp[j * 5 + 2];
            float d2 = fmaf(dx, dx, fmaf(dy, dy, dz * dz));
            if (d2 < R2) {
                cnt += 1.f;
                const float* fp = fraw + (size_t)(b * NPT + nbase + j) * 32;
#pragma unroll
                for (int c = 0; c < 32; ++c) acc[c] += fp[c];
            }
        }
        __syncthreads();
    }
    float* dst = feats + (size_t)row * 352 + 256;
#pragma unroll
    for (int c = 0; c < 32; ++c) if (acc[c] != 0.f) atomicAdd(dst + c, acc[c]);
    if (cnt != 0.f) atomicAdd(cntR + row, cnt);
}

// ---------------- K6: conv3 radius aggregation ----------------
__global__ void k_c3agg(const float* __restrict__ conv3, const float* __restrict__ kp,
                        const float* __restrict__ gc3, float* __restrict__ feats,
                        float* __restrict__ cntC) {
    __shared__ float sq[256 * 3];
    int bid = blockIdx.x;
    int b = bid >> 7, kb = (bid >> 4) & 7, s = bid & 15;
    int t = threadIdx.x;
    int kk = kb * 256 + t, row = b * KP + kk;
    float kx = kp[row * 3], ky = kp[row * 3 + 1], kz = kp[row * 3 + 2];
    float acc[64];
#pragma unroll
    for (int c = 0; c < 64; ++c) acc[c] = 0.f;
    float cnt = 0.f;
    const float R2 = 1.6f * 1.6f;
    for (int tile = 0; tile < 2; ++tile) {
        int nbase = s * 512 + tile * 256;
        const float* src = conv3 + (size_t)(b * MPT + nbase + t) * 67;
        sq[t * 3] = src[0]; sq[t * 3 + 1] = src[1]; sq[t * 3 + 2] = src[2];
        __syncthreads();
        for (int j = 0; j < 256; ++j) {
            float dx = kx - sq[j * 3], dy = ky - sq[j * 3 + 1], dz = kz - sq[j * 3 + 2];
            float d2 = fmaf(dx, dx, fmaf(dy, dy, dz * dz));
            if (d2 < R2) {
                cnt += 1.f;
                const float* gp = gc3 + (size_t)(b * MPT + nbase + j) * 64;
#pragma unroll
                for (int c = 0; c < 64; ++c) acc[c] += gp[c];
            }
        }
        __syncthreads();
    }
    float* dst = feats + (size_t)row * 352 + 288;
#pragma unroll
    for (int c = 0; c < 64; ++c) if (acc[c] != 0.f) atomicAdd(dst + c, acc[c]);
    if (cnt != 0.f) atomicAdd(cntC + row, cnt);
}

// ---------------- K7: fuse GEMM + BN + ReLU ----------------
__global__ void k_fuse(const float* __restrict__ feats, const float* __restrict__ cntR,
                       const float* __restrict__ cntC, const float* __restrict__ Wf,
                       const float* __restrict__ gma, const float* __restrict__ bta,
                       const float* __restrict__ mean, const float* __restrict__ var,
                       float* __restrict__ out) {
    __shared__ float a[2][352];
    int r0 = blockIdx.x * 2;
    int t = threadIdx.x;
    for (int i = t; i < 704; i += 256) {
        int rr = i >= 352 ? 1 : 0;
        int k = i - rr * 352;
        float v = feats[(size_t)(r0 + rr) * 352 + k];
        if (k >= 256) {
            float cn = (k < 288) ? cntR[r0 + rr] : cntC[r0 + rr];
            v = v / fmaxf(cn, 1.0f);
        }
        a[rr][k] = v;
    }
    __syncthreads();
    int r = t >> 7, c = t & 127;
    float s = 0.f;
#pragma unroll 4
    for (int k = 0; k < 352; ++k) s = fmaf(a[r][k], Wf[k * 128 + c], s);
    s = (s - mean[c]) * (1.0f / sqrtf(var[c] + 1e-5f)) * gma[c] + bta[c];
    out[(size_t)(r0 + r) * 128 + c] = fmaxf(s, 0.f);
}

// ---------------- launch ----------------
extern "C" void kernel_launch(void* const* d_in, const int* in_sizes, int n_in,
                              void* d_out, int out_size, void* d_ws, size_t ws_size,
                              hipStream_t stream) {
    const float* pts   = (const float*)d_in[0];
    const float* bbox  = (const float*)d_in[1];
    const float* sf    = (const float*)d_in[2];
    const float* conv3 = (const float*)d_in[3];
    const float* Wraw  = (const float*)d_in[4];
    const float* braw  = (const float*)d_in[5];
    const float* Wc3   = (const float*)d_in[6];
    const float* bc3   = (const float*)d_in[7];
    const float* Wf    = (const float*)d_in[8];
    const float* gma   = (const float*)d_in[9];
    const float* bta   = (const float*)d_in[10];
    const float* mean  = (const float*)d_in[11];
    const float* var   = (const float*)d_in[12];

    float* wsf   = (float*)d_ws;
    float* feats = wsf;
    float* cntR  = wsf + CNTR_OFF;
    float* cntC  = wsf + CNTC_OFF;
    float* fraw  = wsf + FRAW_OFF;
    float* gc3   = wsf + GC3_OFF;
    unsigned char* flags = (unsigned char*)(wsf + FLAGS_F_OFF);

    float* outp  = (float*)d_out;
    float* kpOut = outp + OUT_KP_OFF;

    // zero feats + counters (atomically accumulated later)
    hipMemsetAsync(d_ws, 0, (size_t)(FEATS_LEN + 8192) * 4, stream);

    k_flags<<<BN_ * 64, 256, 0, stream>>>(pts, bbox, flags);
    k_fps<<<BN_, 1024, 0, stream>>>(pts, flags, kpOut);
    k_bilinear<<<BN_ * KP, 256, 0, stream>>>(sf, kpOut, feats);
    k_fraw<<<(BN_ * NPT * 32) / 256, 256, 0, stream>>>(pts, Wraw, braw, fraw);
    k_gc3<<<(BN_ * MPT) / 4, 256, 0, stream>>>(conv3, Wc3, bc3, gc3);
    k_rawagg<<<BN_ * 128, 256, 0, stream>>>(pts, kpOut, fraw, feats, cntR);
    k_c3agg<<<BN_ * 128, 256, 0, stream>>>(conv3, kpOut, gc3, feats, cntC);
    k_fuse<<<2048, 256, 0, stream>>>(feats, cntR, cntC, Wf, gma, bta, mean, var, outp);
}

// Round 2
// 3083.024 us; speedup vs baseline: 1.0092x; 1.0092x over previous
//
#include <hip/hip_runtime.h>
#include <stdint.h>

#define BN_ 2
#define NPT 16384
#define MPT 8192
#define NROI 128
#define KP 2048
#define CAP 5184   // LDS mirror capacity for winner broadcast (3*CAP*4 = 62208 B)
#define MAXS 32    // max compacted slots per thread (256 thr -> V <= 8192)

// ---- workspace layout (float offsets) ----
#define FEATS_LEN (4096*352)
#define CNTR_OFF  (FEATS_LEN)
#define CNTC_OFF  (CNTR_OFF + 4096)
#define FRAW_OFF  (CNTC_OFF + 4096)
#define FRAW_LEN  (BN_*NPT*32)
#define GC3_OFF   (FRAW_OFF + FRAW_LEN)
#define GC3_LEN   (BN_*MPT*64)
#define FLAGS_F_OFF (GC3_OFF + GC3_LEN)      // flags (bytes) at this float offset
#define CX_OFF    (FLAGS_F_OFF + (BN_*NPT)/4)
#define CY_OFF    (CX_OFF + BN_*NPT)
#define CZ_OFF    (CY_OFF + BN_*NPT)
#define OUT_KP_OFF (4096*128)                // keypoints region inside d_out

// ---------------- helpers ----------------
__device__ __forceinline__ unsigned ordf(float f) {
    unsigned b = __float_as_uint(f);
    return b ^ ((unsigned)(((int)b) >> 31) | 0x80000000u);
}
__device__ __forceinline__ unsigned long long shflxor64(unsigned long long v, int m) {
    unsigned lo = __shfl_xor((unsigned)v, m, 64);
    unsigned hi = __shfl_xor((unsigned)(v >> 32), m, 64);
    return ((unsigned long long)hi << 32) | lo;
}
__device__ __forceinline__ unsigned long long wave_max64(unsigned long long k) {
#pragma unroll
    for (int m = 32; m >= 1; m >>= 1) {
        unsigned long long o = shflxor64(k, m);
        if (o > k) k = o;
    }
    return k;
}

// ---------------- K1: ROI validity flags (bit-exact vs reference) ----------------
__global__ void k_flags(const float* __restrict__ pts, const float* __restrict__ bbox,
                        unsigned char* __restrict__ flags) {
#pragma clang fp contract(off)
    __shared__ float rx[NROI], ry[NROI], rz[NROI], rt[NROI];
    int b = blockIdx.x >> 6;
    int t = threadIdx.x;
    if (t < NROI) {
        const float* rr = bbox + (size_t)(b * NROI + t) * 7;
        rx[t] = rr[0]; ry[t] = rr[1]; rz[t] = rr[2];
        float hx = rr[3] * 0.5f, hy = rr[4] * 0.5f, hz = rr[5] * 0.5f;
        rt[t] = sqrtf(((hx * hx) + (hy * hy)) + (hz * hz)) + 2.4f;
    }
    __syncthreads();
    int p = (blockIdx.x & 63) * 256 + t;
    const float* pr = pts + (size_t)(b * NPT + p) * 5;
    float x = pr[0], y = pr[1], z = pr[2];
    float mind = 3.4e38f, th = 0.f;
    for (int r = 0; r < NROI; ++r) {
        float dx = x - rx[r], dy = y - ry[r], dz = z - rz[r];
        float ds = sqrtf(((dx * dx) + (dy * dy)) + (dz * dz));
        if (ds < mind) { mind = ds; th = rt[r]; }   // strict < : first-min == np.argmin
    }
    flags[b * NPT + p] = (mind < th) ? 1 : 0;
}

// ---------------- K2: compaction (via global ws) + exact FPS ----------------
// 256 threads = 4 waves = 1 wave/SIMD: minimal reduction replication.
__global__ void __launch_bounds__(256, 1)
k_fps(const float* __restrict__ pts, const unsigned char* __restrict__ flags,
      float* __restrict__ cxg, float* __restrict__ cyg, float* __restrict__ czg,
      float* __restrict__ kpOut) {
#pragma clang fp contract(off)
    __shared__ float sx[CAP], sy[CAP], sz[CAP];   // LDS mirror of first CAP compacted pts
    __shared__ unsigned long long redK[2][4];
    __shared__ int wtot[4];

    int b = blockIdx.x;
    int t = threadIdx.x;
    int lane = t & 63, w = t >> 6;
    int chunk = t * 64;   // 64 contiguous input points per thread
    const float* pbase = pts + (size_t)b * NPT * 5;
    const unsigned char* fbase = flags + b * NPT;
    float* cx = cxg + (size_t)b * NPT;
    float* cy = cyg + (size_t)b * NPT;
    float* cz = czg + (size_t)b * NPT;

    // ---- pass 1: count valid in my chunk ----
    int cnt = 0;
    for (int j = 0; j < 64; ++j) cnt += fbase[chunk + j] ? 1 : 0;
    // wave inclusive scan
    int incl = cnt;
#pragma unroll
    for (int off = 1; off < 64; off <<= 1) {
        int v = __shfl_up(incl, off, 64);
        if (lane >= off) incl += v;
    }
    if (lane == 63) wtot[w] = incl;
    __syncthreads();
    int waveBase = 0, V = 0;
    for (int i = 0; i < 4; ++i) { int wv = wtot[i]; V += wv; if (i < w) waveBase += wv; }
    int pos = waveBase + incl - cnt;

    // ---- pass 2: scatter compacted coords to global ws (+ LDS mirror) ----
    for (int j = 0; j < 64; ++j) {
        if (fbase[chunk + j]) {
            const float* pr = pbase + (size_t)(chunk + j) * 5;
            float x = pr[0], y = pr[1], z = pr[2];
            cx[pos] = x; cy[pos] = y; cz[pos] = z;
            if (pos < CAP) { sx[pos] = x; sy[pos] = y; sz[pos] = z; }
            ++pos;
        }
    }
    __syncthreads();   // drains vmem: global scatter visible to block via L2

    // ---- slot load: strided assignment id = j*256 + t (order-preserving) ----
    int jm = (V + 255) >> 8;   // <= MAXS expected (V <= 8192)
    float px[MAXS], py[MAXS], pz[MAXS], d[MAXS];
#pragma unroll
    for (int j = 0; j < MAXS; ++j) {
        if (j < jm) {
            int id = (j << 8) + t;
            bool in = id < V;
            px[j] = in ? cx[id] : 1e18f;
            py[j] = in ? cy[id] : 1e18f;
            pz[j] = in ? cz[id] : 1e18f;
            d[j]  = in ? 1e10f : -3e38f;
        }
    }

    // ---- prime: argmax over initial d (ties -> lowest gid = first valid) ----
    float bestD = -3.4e38f; int bestJ = 0;
#pragma unroll
    for (int j = 0; j < MAXS; ++j)
        if (j < jm) { if (d[j] > bestD) { bestD = d[j]; bestJ = j; } }
    unsigned gid = (unsigned)((bestJ << 8) + t);
    unsigned long long key =
        ((unsigned long long)ordf(bestD) << 32) | (0xFFFFFFFFu - gid);
    key = wave_max64(key);
    if (lane == 0) redK[0][w] = key;
    __syncthreads();

    float* kout = kpOut + (size_t)b * KP * 3;
    for (int k = 0; k < KP; ++k) {
        int p = k & 1;
        // block winner: scan the 4 wave candidates (uniform broadcast reads)
        unsigned long long e0 = redK[p][0], e1 = redK[p][1];
        unsigned long long e2 = redK[p][2], e3 = redK[p][3];
        unsigned long long m0 = e0 > e1 ? e0 : e1;
        unsigned long long m1 = e2 > e3 ? e2 : e3;
        unsigned long long win = m0 > m1 ? m0 : m1;
        unsigned wgid = 0xFFFFFFFFu - (unsigned)(win & 0xFFFFFFFFull);
        float bx, by, bz;
        if ((int)wgid < CAP) { bx = sx[wgid]; by = sy[wgid]; bz = sz[wgid]; }
        else                 { bx = cx[wgid]; by = cy[wgid]; bz = cz[wgid]; }
        if (t == 0) { kout[k * 3] = bx; kout[k * 3 + 1] = by; kout[k * 3 + 2] = bz; }
        // update + fused local argmax (no fp contraction)
        bestD = -3.4e38f; bestJ = 0;
#pragma unroll
        for (int j = 0; j < MAXS; ++j) {
            if (j < jm) {
                float dx = px[j] - bx, dy = py[j] - by, dz = pz[j] - bz;
                float nd = ((dx * dx) + (dy * dy)) + (dz * dz);
                float dn = fminf(d[j], nd);
                d[j] = dn;
                if (dn > bestD) { bestD = dn; bestJ = j; }
            }
        }
        gid = (unsigned)((bestJ << 8) + t);
        key = ((unsigned long long)ordf(bestD) << 32) | (0xFFFFFFFFu - gid);
        key = wave_max64(key);
        if (lane == 0) redK[p ^ 1][w] = key;
        __syncthreads();
    }
}

// ---------------- K3: bilinear BEV sampling ----------------
__global__ void k_bilinear(const float* __restrict__ sf, const float* __restrict__ kp,
                           float* __restrict__ feats) {
    int bid = blockIdx.x;
    int b = bid >> 11, kk = bid & 2047;
    int c = threadIdx.x;
    const float* kpr = kp + (size_t)(b * KP + kk) * 3;
    float x = kpr[0], y = kpr[1];
    float xi = ((x - (-75.2f)) / 0.1f) / 8.0f;
    float yi = ((y - (-75.2f)) / 0.1f) / 8.0f;
    int x0 = (int)floorf(xi); x0 = min(max(x0, 0), 187);
    int x1 = min(max(x0 + 1, 0), 187);
    int y0 = (int)floorf(yi); y0 = min(max(y0, 0), 187);
    int y1 = min(max(y0 + 1, 0), 187);
    float xf0 = (float)x0, xf1 = (float)x1, yf0 = (float)y0, yf1 = (float)y1;
    float wa = (xf1 - xi) * (yf1 - yi), wb = (xf1 - xi) * (yi - yf0);
    float wc = (xi - xf0) * (yf1 - yi), wd = (xi - xf0) * (yi - yf0);
    const float* plane = sf + (size_t)(b * 256 + c) * 188 * 188;
    float Ia = plane[y0 * 188 + x0], Ib = plane[y1 * 188 + x0];
    float Ic = plane[y0 * 188 + x1], Id = plane[y1 * 188 + x1];
    feats[(size_t)(b * KP + kk) * 352 + c] = Ia * wa + Ib * wb + Ic * wc + Id * wd;
}

// ---------------- K4a: raw point feature MLP ----------------
__global__ void k_fraw(const float* __restrict__ pts, const float* __restrict__ Wr,
                       const float* __restrict__ br, float* __restrict__ fraw) {
    int idx = blockIdx.x * 256 + threadIdx.x;   // < BN_*NPT*32
    int c = idx & 31, n = idx >> 5;
    const float* pr = pts + (size_t)n * 5;
    float v = pr[3] * Wr[c] + pr[4] * Wr[32 + c] + br[c];
    fraw[(size_t)n * 32 + c] = fmaxf(v, 0.f);
}

// ---------------- K4b: conv3 point feature MLP ----------------
__global__ void k_gc3(const float* __restrict__ conv3, const float* __restrict__ Wc,
                      const float* __restrict__ bc, float* __restrict__ gc3) {
    __shared__ float w[4096];
    __shared__ float rf[4][64];
    int t = threadIdx.x;
    for (int i = t; i < 4096; i += 256) w[i] = Wc[i];
    int r = blockIdx.x * 4 + (t >> 6);
    int c = t & 63;
    rf[t >> 6][c] = conv3[(size_t)r * 67 + 3 + c];
    __syncthreads();
    float s = bc[c];
#pragma unroll 8
    for (int k = 0; k < 64; ++k) s = fmaf(rf[t >> 6][k], w[k * 64 + c], s);
    gc3[(size_t)r * 64 + c] = fmaxf(s, 0.f);
}

// ---------------- K5: raw radius aggregation ----------------
__global__ void k_rawagg(const float* __restrict__ pts, const float* __restrict__ kp,
                         const float* __restrict__ fraw, float* __restrict__ feats,
                         float* __restrict__ cntR) {
    __shared__ float sp[2560];
    int bid = blockIdx.x;
    int b = bid >> 7, kb = (bid >> 4) & 7, s = bid & 15;
    int t = threadIdx.x;
    int kk = kb * 256 + t, row = b * KP + kk;
    float kx = kp[row * 3], ky = kp[row * 3 + 1], kz = kp[row * 3 + 2];
    float acc[32];
#pragma unroll
    for (int c = 0; c < 32; ++c) acc[c] = 0.f;
    float cnt = 0.f;
    const float R2 = 0.8f * 0.8f;
    for (int tile = 0; tile < 2; ++tile) {
        int nbase = s * 1024 + tile * 512;
        const float* src = pts + (size_t)(b * NPT + nbase) * 5;
        for (int i = t; i < 2560; i += 256) sp[i] = src[i];
        __syncthreads();
        for (int j = 0; j < 512; ++j) {
            float dx = kx - sp[j * 5], dy = ky - sp[j * 5 + 1], dz = kz - sp[j * 5 + 2];
            float d2 = fmaf(dx, dx, fmaf(dy, dy, dz * dz));
            if (d2 < R2) {
                cnt += 1.f;
                const float* fp = fraw + (size_t)(b * NPT + nbase + j) * 32;
#pragma unroll
                for (int c = 0; c < 32; ++c) acc[c] += fp[c];
            }
        }
        __syncthreads();
    }
    float* dst = feats + (size_t)row * 352 + 256;
#pragma unroll
    for (int c = 0; c < 32; ++c) if (acc[c] != 0.f) atomicAdd(dst + c, acc[c]);
    if (cnt != 0.f) atomicAdd(cntR + row, cnt);
}

// ---------------- K6: conv3 radius aggregation ----------------
__global__ void k_c3agg(const float* __restrict__ conv3, const float* __restrict__ kp,
                        const float* __restrict__ gc3, float* __restrict__ feats,
                        float* __restrict__ cntC) {
    __shared__ float sq[256 * 3];
    int bid = blockIdx.x;
    int b = bid >> 7, kb = (bid >> 4) & 7, s = bid & 15;
    int t = threadIdx.x;
    int kk = kb * 256 + t, row = b * KP + kk;
    float kx = kp[row * 3], ky = kp[row * 3 + 1], kz = kp[row * 3 + 2];
    float acc[64];
#pragma unroll
    for (int c = 0; c < 64; ++c) acc[c] = 0.f;
    float cnt = 0.f;
    const float R2 = 1.6f * 1.6f;
    for (int tile = 0; tile < 2; ++tile) {
        int nbase = s * 512 + tile * 256;
        const float* src = conv3 + (size_t)(b * MPT + nbase + t) * 67;
        sq[t * 3] = src[0]; sq[t * 3 + 1] = src[1]; sq[t * 3 + 2] = src[2];
        __syncthreads();
        for (int j = 0; j < 256; ++j) {
            float dx = kx - sq[j * 3], dy = ky - sq[j * 3 + 1], dz = kz - sq[j * 3 + 2];
            float d2 = fmaf(dx, dx, fmaf(dy, dy, dz * dz));
            if (d2 < R2) {
                cnt += 1.f;
                const float* gp = gc3 + (size_t)(b * MPT + nbase + j) * 64;
#pragma unroll
                for (int c = 0; c < 64; ++c) acc[c] += gp[c];
            }
        }
        __syncthreads();
    }
    float* dst = feats + (size_t)row * 352 + 288;
#pragma unroll
    for (int c = 0; c < 64; ++c) if (acc[c] != 0.f) atomicAdd(dst + c, acc[c]);
    if (cnt != 0.f) atomicAdd(cntC + row, cnt);
}

// ---------------- K7: fuse GEMM + BN + ReLU ----------------
__global__ void k_fuse(const float* __restrict__ feats, const float* __restrict__ cntR,
                       const float* __restrict__ cntC, const float* __restrict__ Wf,
                       const float* __restrict__ gma, const float* __restrict__ bta,
                       const float* __restrict__ mean, const float* __restrict__ var,
                       float* __restrict__ out) {
    __shared__ float a[2][352];
    int r0 = blockIdx.x * 2;
    int t = threadIdx.x;
    for (int i = t; i < 704; i += 256) {
        int rr = i >= 352 ? 1 : 0;
        int k = i - rr * 352;
        float v = feats[(size_t)(r0 + rr) * 352 + k];
        if (k >= 256) {
            float cn = (k < 288) ? cntR[r0 + rr] : cntC[r0 + rr];
            v = v / fmaxf(cn, 1.0f);
        }
        a[rr][k] = v;
    }
    __syncthreads();
    int r = t >> 7, c = t & 127;
    float s = 0.f;
#pragma unroll 4
    for (int k = 0; k < 352; ++k) s = fmaf(a[r][k], Wf[k * 128 + c], s);
    s = (s - mean[c]) * (1.0f / sqrtf(var[c] + 1e-5f)) * gma[c] + bta[c];
    out[(size_t)(r0 + r) * 128 + c] = fmaxf(s, 0.f);
}

// ---------------- launch ----------------
extern "C" void kernel_launch(void* const* d_in, const int* in_sizes, int n_in,
                              void* d_out, int out_size, void* d_ws, size_t ws_size,
                              hipStream_t stream) {
    const float* pts   = (const float*)d_in[0];
    const float* bbox  = (const float*)d_in[1];
    const float* sf    = (const float*)d_in[2];
    const float* conv3 = (const float*)d_in[3];
    const float* Wraw  = (const float*)d_in[4];
    const float* braw  = (const float*)d_in[5];
    const float* Wc3   = (const float*)d_in[6];
    const float* bc3   = (const float*)d_in[7];
    const float* Wf    = (const float*)d_in[8];
    const float* gma   = (const float*)d_in[9];
    const float* bta   = (const float*)d_in[10];
    const float* mean  = (const float*)d_in[11];
    const float* var   = (const float*)d_in[12];

    float* wsf   = (float*)d_ws;
    float* feats = wsf;
    float* cntR  = wsf + CNTR_OFF;
    float* cntC  = wsf + CNTC_OFF;
    float* fraw  = wsf + FRAW_OFF;
    float* gc3   = wsf + GC3_OFF;
    unsigned char* flags = (unsigned char*)(wsf + FLAGS_F_OFF);
    float* cxg   = wsf + CX_OFF;
    float* cyg   = wsf + CY_OFF;
    float* czg   = wsf + CZ_OFF;

    float* outp  = (float*)d_out;
    float* kpOut = outp + OUT_KP_OFF;

    // zero feats + counters (atomically accumulated later)
    hipMemsetAsync(d_ws, 0, (size_t)(FEATS_LEN + 8192) * 4, stream);

    k_flags<<<BN_ * 64, 256, 0, stream>>>(pts, bbox, flags);
    k_fps<<<BN_, 256, 0, stream>>>(pts, flags, cxg, cyg, czg, kpOut);
    k_bilinear<<<BN_ * KP, 256, 0, stream>>>(sf, kpOut, feats);
    k_fraw<<<(BN_ * NPT * 32) / 256, 256, 0, stream>>>(pts, Wraw, braw, fraw);
    k_gc3<<<(BN_ * MPT) / 4, 256, 0, stream>>>(conv3, Wc3, bc3, gc3);
    k_rawagg<<<BN_ * 128, 256, 0, stream>>>(pts, kpOut, fraw, feats, cntR);
    k_c3agg<<<BN_ * 128, 256, 0, stream>>>(conv3, kpOut, gc3, feats, cntC);
    k_fuse<<<2048, 256, 0, stream>>>(feats, cntR, cntC, Wf, gma, bta, mean, var, outp);
}

// Round 3
// 2213.122 us; speedup vs baseline: 1.4059x; 1.3931x over previous
//
#include <hip/hip_runtime.h>
#include <stdint.h>

#define BN_ 2
#define NPT 16384
#define MPT 8192
#define NROI 128
#define KP 2048
#define CAP 5184   // LDS mirror capacity for winner xyz broadcast (3*CAP*4 = 62208 B)

// ---- workspace layout (float offsets) ----
#define FEATS_LEN (4096*352)
#define CNTR_OFF  (FEATS_LEN)
#define CNTC_OFF  (CNTR_OFF + 4096)
#define FRAW_OFF  (CNTC_OFF + 4096)
#define FRAW_LEN  (BN_*NPT*32)
#define GC3_OFF   (FRAW_OFF + FRAW_LEN)
#define GC3_LEN   (BN_*MPT*64)
#define FLAGS_F_OFF (GC3_OFF + GC3_LEN)      // flags (bytes) at this float offset
#define CX_OFF    (FLAGS_F_OFF + (BN_*NPT)/4)
#define CY_OFF    (CX_OFF + BN_*NPT)
#define CZ_OFF    (CY_OFF + BN_*NPT)
#define OUT_KP_OFF (4096*128)                // keypoints region inside d_out

// ---------------- helpers ----------------
__device__ __forceinline__ unsigned ordf(float f) {
    unsigned b = __float_as_uint(f);
    return b ^ ((unsigned)(((int)b) >> 31) | 0x80000000u);
}

// DPP move: lanes without a source keep their current value (old = v).
template <int CTRL>
__device__ __forceinline__ unsigned dppmov(unsigned v) {
    return (unsigned)__builtin_amdgcn_update_dpp((int)v, (int)v, CTRL, 0xF, 0xF, false);
}
// Wave64 max via DPP (row_shr 1/2/4/8, row_bcast15, row_bcast31); result in lane 63,
// broadcast to all lanes via readlane.
__device__ __forceinline__ unsigned wave_umax_dpp(unsigned v) {
    unsigned o;
    o = dppmov<0x111>(v); v = (o > v) ? o : v;   // row_shr:1
    o = dppmov<0x112>(v); v = (o > v) ? o : v;   // row_shr:2
    o = dppmov<0x114>(v); v = (o > v) ? o : v;   // row_shr:4
    o = dppmov<0x118>(v); v = (o > v) ? o : v;   // row_shr:8
    o = dppmov<0x142>(v); v = (o > v) ? o : v;   // row_bcast:15
    o = dppmov<0x143>(v); v = (o > v) ? o : v;   // row_bcast:31
    return (unsigned)__builtin_amdgcn_readlane((int)v, 63);
}

// ---------------- K1: ROI validity flags (bit-exact vs reference) ----------------
__global__ void k_flags(const float* __restrict__ pts, const float* __restrict__ bbox,
                        unsigned char* __restrict__ flags) {
#pragma clang fp contract(off)
    __shared__ float rx[NROI], ry[NROI], rz[NROI], rt[NROI];
    int b = blockIdx.x >> 6;
    int t = threadIdx.x;
    if (t < NROI) {
        const float* rr = bbox + (size_t)(b * NROI + t) * 7;
        rx[t] = rr[0]; ry[t] = rr[1]; rz[t] = rr[2];
        float hx = rr[3] * 0.5f, hy = rr[4] * 0.5f, hz = rr[5] * 0.5f;
        rt[t] = sqrtf(((hx * hx) + (hy * hy)) + (hz * hz)) + 2.4f;
    }
    __syncthreads();
    int p = (blockIdx.x & 63) * 256 + t;
    const float* pr = pts + (size_t)(b * NPT + p) * 5;
    float x = pr[0], y = pr[1], z = pr[2];
    float mind = 3.4e38f, th = 0.f;
    for (int r = 0; r < NROI; ++r) {
        float dx = x - rx[r], dy = y - ry[r], dz = z - rz[r];
        float ds = sqrtf(((dx * dx) + (dy * dy)) + (dz * dz));
        if (ds < mind) { mind = ds; th = rt[r]; }   // strict < : first-min == np.argmin
    }
    flags[b * NPT + p] = (mind < th) ? 1 : 0;
}

// ---------------- FPS inner loop, compile-time slot count NS ----------------
// All slot arrays fully unrolled with constant indices -> guaranteed VGPRs.
template <int NS>
__device__ __forceinline__ void fps_loop(
    int t, int lane, int w, int V,
    const float* __restrict__ cx, const float* __restrict__ cy,
    const float* __restrict__ cz,
    const float* sxm, const float* sym, const float* szm,   // LDS mirrors
    uint2 (*rkey)[4],                                        // LDS, [2][4]
    float* __restrict__ kout) {
#pragma clang fp contract(off)
    float px[NS], py[NS], pz[NS], d[NS];
#pragma unroll
    for (int j = 0; j < NS; ++j) {
        int id = (j << 8) + t;
        bool in = id < V;
        px[j] = in ? cx[id] : 1e18f;
        py[j] = in ? cy[id] : 1e18f;
        pz[j] = in ? cz[id] : 1e18f;
        d[j]  = in ? 1e10f : -3.0e38f;
    }

    // prime: argmax over initial d (ties -> lowest j, then min gid across lanes)
    float bestD = -3.4e38f; int bestJ = 0;
#pragma unroll
    for (int j = 0; j < NS; ++j)
        if (d[j] > bestD) { bestD = d[j]; bestJ = j; }
    unsigned gid = (unsigned)((bestJ << 8) + t);
    unsigned myOrd = ordf(bestD);
    unsigned maxOrd = wave_umax_dpp(myOrd);
    unsigned inv = (myOrd == maxOrd) ? (0xFFFFFFFFu - gid) : 0u;
    unsigned maxInv = wave_umax_dpp(inv);
    if (lane == 0) rkey[0][w] = make_uint2(maxOrd, maxInv);
    __syncthreads();

    for (int k = 0; k < KP; ++k) {
        int p = k & 1;
        // block winner among 4 wave candidates (uniform, u64-key semantics)
        uint2 c0 = rkey[p][0], c1 = rkey[p][1], c2 = rkey[p][2], c3 = rkey[p][3];
        uint2 m0 = (c1.x > c0.x || (c1.x == c0.x && c1.y > c0.y)) ? c1 : c0;
        uint2 m1 = (c3.x > c2.x || (c3.x == c2.x && c3.y > c2.y)) ? c3 : c2;
        uint2 win = (m1.x > m0.x || (m1.x == m0.x && m1.y > m0.y)) ? m1 : m0;
        unsigned wid = 0xFFFFFFFFu - win.y;
        float bx, by, bz;
        if ((int)wid < CAP) { bx = sxm[wid]; by = sym[wid]; bz = szm[wid]; }
        else                { bx = cx[wid];  by = cy[wid];  bz = cz[wid];  }
        if (t == 0) { kout[k * 3] = bx; kout[k * 3 + 1] = by; kout[k * 3 + 2] = bz; }

        // update + fused local argmax (exact: no fp contraction)
        bestD = -3.4e38f; bestJ = 0;
#pragma unroll
        for (int j = 0; j < NS; ++j) {
            float dx = px[j] - bx, dy = py[j] - by, dz = pz[j] - bz;
            float nd = ((dx * dx) + (dy * dy)) + (dz * dz);
            float dn = fminf(d[j], nd);
            d[j] = dn;
            if (dn > bestD) { bestD = dn; bestJ = j; }
        }
        gid = (unsigned)((bestJ << 8) + t);
        myOrd = ordf(bestD);
        maxOrd = wave_umax_dpp(myOrd);
        inv = (myOrd == maxOrd) ? (0xFFFFFFFFu - gid) : 0u;
        maxInv = wave_umax_dpp(inv);
        if (lane == 0) rkey[p ^ 1][w] = make_uint2(maxOrd, maxInv);
        __syncthreads();
    }
}

// ---------------- K2: compaction (via global ws) + exact FPS ----------------
// 256 threads = 4 waves = 1 wave/SIMD.
__global__ void __launch_bounds__(256, 1)
k_fps(const float* __restrict__ pts, const unsigned char* __restrict__ flags,
      float* __restrict__ cxg, float* __restrict__ cyg, float* __restrict__ czg,
      float* __restrict__ kpOut) {
#pragma clang fp contract(off)
    __shared__ float sx[CAP], sy[CAP], sz[CAP];   // mirror of first CAP compacted pts
    __shared__ uint2 rkey[2][4];
    __shared__ int wtot[4];

    int b = blockIdx.x;
    int t = threadIdx.x;
    int lane = t & 63, w = t >> 6;
    int chunk = t * 64;   // 64 contiguous input points per thread
    const float* pbase = pts + (size_t)b * NPT * 5;
    const unsigned char* fbase = flags + b * NPT;
    float* cx = cxg + (size_t)b * NPT;
    float* cy = cyg + (size_t)b * NPT;
    float* cz = czg + (size_t)b * NPT;

    // pass 1: count valid in my chunk
    int cnt = 0;
    for (int j = 0; j < 64; ++j) cnt += fbase[chunk + j] ? 1 : 0;
    int incl = cnt;
#pragma unroll
    for (int off = 1; off < 64; off <<= 1) {
        int v = __shfl_up(incl, off, 64);
        if (lane >= off) incl += v;
    }
    if (lane == 63) wtot[w] = incl;
    __syncthreads();
    int waveBase = 0, V = 0;
    for (int i = 0; i < 4; ++i) { int wv = wtot[i]; V += wv; if (i < w) waveBase += wv; }
    int pos = waveBase + incl - cnt;

    // pass 2: stable scatter of compacted coords to global ws (+ LDS mirror)
    for (int j = 0; j < 64; ++j) {
        if (fbase[chunk + j]) {
            const float* pr = pbase + (size_t)(chunk + j) * 5;
            float x = pr[0], y = pr[1], z = pr[2];
            cx[pos] = x; cy[pos] = y; cz[pos] = z;
            if (pos < CAP) { sx[pos] = x; sy[pos] = y; sz[pos] = z; }
            ++pos;
        }
    }
    __syncthreads();   // workgroup fence: scatter visible to block

    float* kout = kpOut + (size_t)b * KP * 3;
    int jm = (V + 255) >> 8;
    if (jm <= 20)      fps_loop<20>(t, lane, w, V, cx, cy, cz, sx, sy, sz, rkey, kout);
    else if (jm <= 24) fps_loop<24>(t, lane, w, V, cx, cy, cz, sx, sy, sz, rkey, kout);
    else if (jm <= 28) fps_loop<28>(t, lane, w, V, cx, cy, cz, sx, sy, sz, rkey, kout);
    else               fps_loop<32>(t, lane, w, V, cx, cy, cz, sx, sy, sz, rkey, kout);
}

// ---------------- K3: bilinear BEV sampling ----------------
__global__ void k_bilinear(const float* __restrict__ sf, const float* __restrict__ kp,
                           float* __restrict__ feats) {
    int bid = blockIdx.x;
    int b = bid >> 11, kk = bid & 2047;
    int c = threadIdx.x;
    const float* kpr = kp + (size_t)(b * KP + kk) * 3;
    float x = kpr[0], y = kpr[1];
    float xi = ((x - (-75.2f)) / 0.1f) / 8.0f;
    float yi = ((y - (-75.2f)) / 0.1f) / 8.0f;
    int x0 = (int)floorf(xi); x0 = min(max(x0, 0), 187);
    int x1 = min(max(x0 + 1, 0), 187);
    int y0 = (int)floorf(yi); y0 = min(max(y0, 0), 187);
    int y1 = min(max(y0 + 1, 0), 187);
    float xf0 = (float)x0, xf1 = (float)x1, yf0 = (float)y0, yf1 = (float)y1;
    float wa = (xf1 - xi) * (yf1 - yi), wb = (xf1 - xi) * (yi - yf0);
    float wc = (xi - xf0) * (yf1 - yi), wd = (xi - xf0) * (yi - yf0);
    const float* plane = sf + (size_t)(b * 256 + c) * 188 * 188;
    float Ia = plane[y0 * 188 + x0], Ib = plane[y1 * 188 + x0];
    float Ic = plane[y0 * 188 + x1], Id = plane[y1 * 188 + x1];
    feats[(size_t)(b * KP + kk) * 352 + c] = Ia * wa + Ib * wb + Ic * wc + Id * wd;
}

// ---------------- K4a: raw point feature MLP ----------------
__global__ void k_fraw(const float* __restrict__ pts, const float* __restrict__ Wr,
                       const float* __restrict__ br, float* __restrict__ fraw) {
    int idx = blockIdx.x * 256 + threadIdx.x;   // < BN_*NPT*32
    int c = idx & 31, n = idx >> 5;
    const float* pr = pts + (size_t)n * 5;
    float v = pr[3] * Wr[c] + pr[4] * Wr[32 + c] + br[c];
    fraw[(size_t)n * 32 + c] = fmaxf(v, 0.f);
}

// ---------------- K4b: conv3 point feature MLP ----------------
__global__ void k_gc3(const float* __restrict__ conv3, const float* __restrict__ Wc,
                      const float* __restrict__ bc, float* __restrict__ gc3) {
    __shared__ float w[4096];
    __shared__ float rf[4][64];
    int t = threadIdx.x;
    for (int i = t; i < 4096; i += 256) w[i] = Wc[i];
    int r = blockIdx.x * 4 + (t >> 6);
    int c = t & 63;
    rf[t >> 6][c] = conv3[(size_t)r * 67 + 3 + c];
    __syncthreads();
    float s = bc[c];
#pragma unroll 8
    for (int k = 0; k < 64; ++k) s = fmaf(rf[t >> 6][k], w[k * 64 + c], s);
    gc3[(size_t)r * 64 + c] = fmaxf(s, 0.f);
}

// ---------------- K5: raw radius aggregation ----------------
__global__ void k_rawagg(const float* __restrict__ pts, const float* __restrict__ kp,
                         const float* __restrict__ fraw, float* __restrict__ feats,
                         float* __restrict__ cntR) {
    __shared__ float sp[2560];
    int bid = blockIdx.x;
    int b = bid >> 7, kb = (bid >> 4) & 7, s = bid & 15;
    int t = threadIdx.x;
    int kk = kb * 256 + t, row = b * KP + kk;
    float kx = kp[row * 3], ky = kp[row * 3 + 1], kz = kp[row * 3 + 2];
    float acc[32];
#pragma unroll
    for (int c = 0; c < 32; ++c) acc[c] = 0.f;
    float cnt = 0.f;
    const float R2 = 0.8f * 0.8f;
    for (int tile = 0; tile < 2; ++tile) {
        int nbase = s * 1024 + tile * 512;
        const float* src = pts + (size_t)(b * NPT + nbase) * 5;
        for (int i = t; i < 2560; i += 256) sp[i] = src[i];
        __syncthreads();
        for (int j = 0; j < 512; ++j) {
            float dx = kx - sp[j * 5], dy = ky - sp[j * 5 + 1], dz = kz - sp[j * 5 + 2];
            float d2 = fmaf(dx, dx, fmaf(dy, dy, dz * dz));
            if (d2 < R2) {
                cnt += 1.f;
                const float* fp = fraw + (size_t)(b * NPT + nbase + j) * 32;
#pragma unroll
                for (int c = 0; c < 32; ++c) acc[c] += fp[c];
            }
        }
        __syncthreads();
    }
    float* dst = feats + (size_t)row * 352 + 256;
#pragma unroll
    for (int c = 0; c < 32; ++c) if (acc[c] != 0.f) atomicAdd(dst + c, acc[c]);
    if (cnt != 0.f) atomicAdd(cntR + row, cnt);
}

// ---------------- K6: conv3 radius aggregation ----------------
__global__ void k_c3agg(const float* __restrict__ conv3, const float* __restrict__ kp,
                        const float* __restrict__ gc3, float* __restrict__ feats,
                        float* __restrict__ cntC) {
    __shared__ float sq[256 * 3];
    int bid = blockIdx.x;
    int b = bid >> 7, kb = (bid >> 4) & 7, s = bid & 15;
    int t = threadIdx.x;
    int kk = kb * 256 + t, row = b * KP + kk;
    float kx = kp[row * 3], ky = kp[row * 3 + 1], kz = kp[row * 3 + 2];
    float acc[64];
#pragma unroll
    for (int c = 0; c < 64; ++c) acc[c] = 0.f;
    float cnt = 0.f;
    const float R2 = 1.6f * 1.6f;
    for (int tile = 0; tile < 2; ++tile) {
        int nbase = s * 512 + tile * 256;
        const float* src = conv3 + (size_t)(b * MPT + nbase + t) * 67;
        sq[t * 3] = src[0]; sq[t * 3 + 1] = src[1]; sq[t * 3 + 2] = src[2];
        __syncthreads();
        for (int j = 0; j < 256; ++j) {
            float dx = kx - sq[j * 3], dy = ky - sq[j * 3 + 1], dz = kz - sq[j * 3 + 2];
            float d2 = fmaf(dx, dx, fmaf(dy, dy, dz * dz));
            if (d2 < R2) {
                cnt += 1.f;
                const float* gp = gc3 + (size_t)(b * MPT + nbase + j) * 64;
#pragma unroll
                for (int c = 0; c < 64; ++c) acc[c] += gp[c];
            }
        }
        __syncthreads();
    }
    float* dst = feats + (size_t)row * 352 + 288;
#pragma unroll
    for (int c = 0; c < 64; ++c) if (acc[c] != 0.f) atomicAdd(dst + c, acc[c]);
    if (cnt != 0.f) atomicAdd(cntC + row, cnt);
}

// ---------------- K7: fuse GEMM + BN + ReLU ----------------
__global__ void k_fuse(const float* __restrict__ feats, const float* __restrict__ cntR,
                       const float* __restrict__ cntC, const float* __restrict__ Wf,
                       const float* __restrict__ gma, const float* __restrict__ bta,
                       const float* __restrict__ mean, const float* __restrict__ var,
                       float* __restrict__ out) {
    __shared__ float a[2][352];
    int r0 = blockIdx.x * 2;
    int t = threadIdx.x;
    for (int i = t; i < 704; i += 256) {
        int rr = i >= 352 ? 1 : 0;
        int k = i - rr * 352;
        float v = feats[(size_t)(r0 + rr) * 352 + k];
        if (k >= 256) {
            float cn = (k < 288) ? cntR[r0 + rr] : cntC[r0 + rr];
            v = v / fmaxf(cn, 1.0f);
        }
        a[rr][k] = v;
    }
    __syncthreads();
    int r = t >> 7, c = t & 127;
    float s = 0.f;
#pragma unroll 4
    for (int k = 0; k < 352; ++k) s = fmaf(a[r][k], Wf[k * 128 + c], s);
    s = (s - mean[c]) * (1.0f / sqrtf(var[c] + 1e-5f)) * gma[c] + bta[c];
    out[(size_t)(r0 + r) * 128 + c] = fmaxf(s, 0.f);
}

// ---------------- launch ----------------
extern "C" void kernel_launch(void* const* d_in, const int* in_sizes, int n_in,
                              void* d_out, int out_size, void* d_ws, size_t ws_size,
                              hipStream_t stream) {
    const float* pts   = (const float*)d_in[0];
    const float* bbox  = (const float*)d_in[1];
    const float* sf    = (const float*)d_in[2];
    const float* conv3 = (const float*)d_in[3];
    const float* Wraw  = (const float*)d_in[4];
    const float* braw  = (const float*)d_in[5];
    const float* Wc3   = (const float*)d_in[6];
    const float* bc3   = (const float*)d_in[7];
    const float* Wf    = (const float*)d_in[8];
    const float* gma   = (const float*)d_in[9];
    const float* bta   = (const float*)d_in[10];
    const float* mean  = (const float*)d_in[11];
    const float* var   = (const float*)d_in[12];

    float* wsf   = (float*)d_ws;
    float* feats = wsf;
    float* cntR  = wsf + CNTR_OFF;
    float* cntC  = wsf + CNTC_OFF;
    float* fraw  = wsf + FRAW_OFF;
    float* gc3   = wsf + GC3_OFF;
    unsigned char* flags = (unsigned char*)(wsf + FLAGS_F_OFF);
    float* cxg   = wsf + CX_OFF;
    float* cyg   = wsf + CY_OFF;
    float* czg   = wsf + CZ_OFF;

    float* outp  = (float*)d_out;
    float* kpOut = outp + OUT_KP_OFF;

    // zero feats + counters (atomically accumulated later)
    hipMemsetAsync(d_ws, 0, (size_t)(FEATS_LEN + 8192) * 4, stream);

    k_flags<<<BN_ * 64, 256, 0, stream>>>(pts, bbox, flags);
    k_fps<<<BN_, 256, 0, stream>>>(pts, flags, cxg, cyg, czg, kpOut);
    k_bilinear<<<BN_ * KP, 256, 0, stream>>>(sf, kpOut, feats);
    k_fraw<<<(BN_ * NPT * 32) / 256, 256, 0, stream>>>(pts, Wraw, braw, fraw);
    k_gc3<<<(BN_ * MPT) / 4, 256, 0, stream>>>(conv3, Wc3, bc3, gc3);
    k_rawagg<<<BN_ * 128, 256, 0, stream>>>(pts, kpOut, fraw, feats, cntR);
    k_c3agg<<<BN_ * 128, 256, 0, stream>>>(conv3, kpOut, gc3, feats, cntC);
    k_fuse<<<2048, 256, 0, stream>>>(feats, cntR, cntC, Wf, gma, bta, mean, var, outp);
}